// Round 13
// baseline (936.583 us; speedup 1.0000x reference)
//
#include <hip/hip_runtime.h>
#include <math.h>

// Dims (fixed by the problem)
#define HH   50          // hidden
#define GG   150         // 3H
#define XGS  152         // xg row stride (padded)
#define TTT  2048        // T
#define NB   64          // batch B
#define MTOT (TTT*NB)    // 131072 rows per layer
#define D0   128         // layer-0 input dim

static __device__ __forceinline__ float sigm(float x) {
    return 1.f / (1.f + __expf(-x));
}
static __device__ __forceinline__ float tanh_f(float x) {
    return 1.f - 2.f / (__expf(2.f * x) + 1.f);   // saturates correctly at +/-inf
}

static __device__ __forceinline__ void fma4(float4& a, float s, const float4& w) {
    a.x += s * w.x; a.y += s * w.y; a.z += s * w.z; a.w += s * w.w;
}

static __device__ __forceinline__ float bcast(float v, int k) {
    return __uint_as_float(__builtin_amdgcn_readlane(__float_as_uint(v), k));
}

// ---------------- Layer-0 input projection: Xg = X0 @ W + bi ----------------
// (proven, ~110 us)
__global__ __launch_bounds__(256) void proj0_kernel(
    const float* __restrict__ x,              // [64,2048,128] f32
    const float* __restrict__ W,              // [128,150] f32
    const float* __restrict__ bias,           // [2,150] f32 (bi = bias[0])
    float* __restrict__ xg)                   // [MTOT,XGS] f32
{
    __shared__ float xs[128][36];             // k-quarter of x, stride 36 (18.4 KB)
    __shared__ float Wp[32][32];              // k-quarter of W cols for this tile (4 KB)
    const int tid  = threadIdx.x;
    const int m0   = blockIdx.x * 128;
    const int c0   = blockIdx.y * 32;         // col-tile base: 0,32,64,96,128
    const int rowq = tid >> 3;                // 0..31
    const int colq = tid & 7;                 // 0..7

    float4 acc[4];
    #pragma unroll
    for (int j = 0; j < 4; ++j) acc[j] = make_float4(0.f, 0.f, 0.f, 0.f);

    for (int q = 0; q < 4; ++q) {             // K quarters of 32
        if (q) __syncthreads();
        for (int i = tid; i < 128 * 8; i += 256) {
            int r = i >> 3, k4 = (i & 7) * 4;
            int row = m0 + r, t = row >> 6, b = row & 63;
            *(float4*)&xs[r][k4] =
                *(const float4*)&x[((size_t)b * TTT + t) * D0 + q * 32 + k4];
        }
        for (int i = tid; i < 32 * 32; i += 256) {
            int k = i >> 5, c = i & 31, gc = c0 + c;
            Wp[k][c] = (gc < GG) ? W[(q * 32 + k) * GG + gc] : 0.f;
        }
        __syncthreads();
        const float* xr0 = xs[rowq * 4 + 0];
        const float* xr1 = xs[rowq * 4 + 1];
        const float* xr2 = xs[rowq * 4 + 2];
        const float* xr3 = xs[rowq * 4 + 3];
        for (int k = 0; k < 32; k += 4) {
            float4 w0 = *(const float4*)&Wp[k + 0][colq * 4];
            float4 w1 = *(const float4*)&Wp[k + 1][colq * 4];
            float4 w2 = *(const float4*)&Wp[k + 2][colq * 4];
            float4 w3 = *(const float4*)&Wp[k + 3][colq * 4];
            float4 x0 = *(const float4*)&xr0[k];
            float4 x1 = *(const float4*)&xr1[k];
            float4 x2 = *(const float4*)&xr2[k];
            float4 x3 = *(const float4*)&xr3[k];
            fma4(acc[0], x0.x, w0); fma4(acc[0], x0.y, w1);
            fma4(acc[0], x0.z, w2); fma4(acc[0], x0.w, w3);
            fma4(acc[1], x1.x, w0); fma4(acc[1], x1.y, w1);
            fma4(acc[1], x1.z, w2); fma4(acc[1], x1.w, w3);
            fma4(acc[2], x2.x, w0); fma4(acc[2], x2.y, w1);
            fma4(acc[2], x2.z, w2); fma4(acc[2], x2.w, w3);
            fma4(acc[3], x3.x, w0); fma4(acc[3], x3.y, w1);
            fma4(acc[3], x3.z, w2); fma4(acc[3], x3.w, w3);
        }
    }
    const int cc = c0 + colq * 4;
    if (cc <= XGS - 4) {                      // cc <= 148; cols 150/151 unread pad
        float4 bv = *(const float4*)&bias[cc];
        #pragma unroll
        for (int j = 0; j < 4; ++j) {
            float4 o;
            o.x = acc[j].x + bv.x; o.y = acc[j].y + bv.y;
            o.z = acc[j].z + bv.z; o.w = acc[j].w + bv.w;
            *(float4*)&xg[(size_t)(m0 + rowq * 4 + j) * XGS + cc] = o;
        }
    }
}

// ---------------- Layer-0 GRU: h in registers, readlane broadcast ----------------
// R5-proven config <4,1>: 2048 waves = 2/SIMD (L0's structural max; R9's
// switch to <4,2> was a hidden regression to 1/SIMD, 139 us).
template<int WPB, int RPW>
__global__ __launch_bounds__(WPB * 64) void gru_reg(
    const float* __restrict__ xg,             // [dn*Nbatch, XGS] f32 (includes bi)
    const float* __restrict__ U,              // [50,150] f32
    const float* __restrict__ bias,           // [2,150] f32 (br = bias+150)
    float* __restrict__ Xout,                 // [MTOT,50] f32 time-major
    int dn, int Nbatch, int ngroups)
{
    constexpr int R = WPB * RPW;              // rows per block per group
    __shared__ __align__(16) float Ut[HH][HH][4];   // [k][unit][{z,r,h,0}] 40 KB

    const int tid  = threadIdx.x;
    const int wav  = tid >> 6;
    const int lane = tid & 63;

    for (int i = tid; i < HH * HH; i += WPB * 64)
        Ut[i / HH][i - (i / HH) * HH][3] = 0.f;
    for (int i = tid; i < HH * GG; i += WPB * 64) {
        int k = i / GG, cc = i - k * GG;
        Ut[k][cc % HH][cc / HH] = U[i];       // U cols: [z|r|h] blocks of 50
    }
    __syncthreads();                          // the only block-wide barrier

    const int c  = lane;
    const int cb = (c < HH) ? c : HH - 1;     // clamped for loads (lanes 50..63)

    const float bz  = bias[GG + cb];
    const float brr = bias[GG + HH + cb];
    const float bh  = bias[GG + 2 * HH + cb];

    for (int grp = blockIdx.x; grp < ngroups; grp += gridDim.x) {
        const int row0 = grp * R + wav * RPW;
        float h[RPW];
        #pragma unroll
        for (int j = 0; j < RPW; ++j) h[j] = 0.f;
        size_t obase[RPW];
        #pragma unroll
        for (int j = 0; j < RPW; ++j) {
            int nr = row0 + j;
            obase[j] = ((size_t)((nr >> 6) * dn) * NB + (nr & 63)) * HH + cb;
        }
        const float* gb = xg + (size_t)row0 * XGS;

        float px[RPW], pr[RPW], ph[RPW];
        #pragma unroll
        for (int j = 0; j < RPW; ++j) {       // preload step 0
            const float* g = gb + (size_t)j * XGS;
            px[j] = g[cb]; pr[j] = g[HH + cb]; ph[j] = g[2 * HH + cb];
        }

        for (int s = 0; s < dn; ++s) {
            const int sn = (s + 1 < dn) ? s + 1 : s;
            float nx[RPW], nrr[RPW], nh[RPW];
            #pragma unroll
            for (int j = 0; j < RPW; ++j) {
                const float* g = gb + ((size_t)sn * Nbatch + j) * XGS;
                nx[j] = g[cb]; nrr[j] = g[HH + cb]; nh[j] = g[2 * HH + cb];
            }
            float az[RPW], ar[RPW], ah[RPW];
            #pragma unroll
            for (int j = 0; j < RPW; ++j) { az[j] = bz; ar[j] = brr; ah[j] = bh; }
            #pragma unroll 5
            for (int k = 0; k < HH; ++k) {
                float4 w = *(const float4*)&Ut[k][c < HH ? c : 0][0];
                #pragma unroll
                for (int j = 0; j < RPW; ++j) {
                    float hk = bcast(h[j], k);
                    az[j] += hk * w.x;
                    ar[j] += hk * w.y;
                    ah[j] += hk * w.z;
                }
            }
            #pragma unroll
            for (int j = 0; j < RPW; ++j) {
                float z  = sigm(px[j] + az[j]);
                float r  = sigm(pr[j] + ar[j]);
                float hh = tanh_f(ph[j] + r * ah[j]);
                float hn = z * h[j] + (1.f - z) * hh;
                h[j] = hn;
                if (c < HH) Xout[obase[j] + (size_t)s * NB * HH] = hn;
            }
            #pragma unroll
            for (int j = 0; j < RPW; ++j) { px[j] = nx[j]; pr[j] = nrr[j]; ph[j] = nh[j]; }
        }
    }
}

// ---------------- Fused proj+GRU v2: LDS-broadcast h/x, packed weights ----------------
// R12-proven mechanism. This round: WPB=8 (512 thr, 2 blocks/CU at ~68-75 KB
// LDS) + RPW per layer so total waves >= 4096 -> >=4 waves/SIMD resident
// (R12 analysis: all GRU configs ran at <=2/SIMD -> ds_read->FMA chain
// exposed at full LDS latency; this is the occupancy fix).
template<int WPB, int RPW>
__global__ __launch_bounds__(WPB * 64) void gru_fused2(
    const float* __restrict__ Xin,            // [dn*Nbatch, HH] f32 (prev layer)
    const float* __restrict__ W,              // [50,150] f32
    const float* __restrict__ U,              // [50,150] f32
    const float* __restrict__ bias,           // [2,150] f32
    float* __restrict__ Xout,                 // [MTOT,50] f32 time-major
    int dn, int Nbatch, int ngroups)
{
    constexpr int R  = WPB * RPW;             // rows per block per group
    constexpr int RS = R + 4;                 // padded row stride (16B-aligned)
    __shared__ __align__(16) float UWs[HH][HH][4];  // {Uz,Ur,Uh,Wz} 40 KB
    __shared__ __align__(16) float W2s[HH][HH][2];  // {Wr,Wh}       20 KB
    __shared__ __align__(16) float hsT[HH][RS];     // h state, [unit][col]
    __shared__ __align__(16) float xsT[HH][RS];     // x of current step

    const int tid  = threadIdx.x;
    const int wav  = tid >> 6;
    const int lane = tid & 63;

    for (int i = tid; i < HH * HH; i += WPB * 64) {
        int k = i / HH, cc = i - k * HH;
        const float* u = U + k * GG;
        const float* w = W + k * GG;
        UWs[k][cc][0] = u[cc];
        UWs[k][cc][1] = u[HH + cc];
        UWs[k][cc][2] = u[2 * HH + cc];
        UWs[k][cc][3] = w[cc];
        W2s[k][cc][0] = w[HH + cc];
        W2s[k][cc][1] = w[2 * HH + cc];
    }
    __syncthreads();                          // the only block-wide barrier

    const int c   = lane;
    const int cb  = (c < HH) ? c : HH - 1;
    const bool act = (c < HH);

    const float biz = bias[cb];
    const float bir = bias[HH + cb];
    const float bih = bias[2 * HH + cb];
    const float brz = bias[GG + cb];
    const float brr = bias[GG + HH + cb];
    const float brh = bias[GG + 2 * HH + cb];

    for (int grp = blockIdx.x; grp < ngroups; grp += gridDim.x) {
        const int row0 = grp * R + wav * RPW;
        float h[RPW], px[RPW];
        size_t obase[RPW];
        #pragma unroll
        for (int j = 0; j < RPW; ++j) {
            h[j] = 0.f;
            int nr = row0 + j;
            obase[j] = ((size_t)((nr >> 6) * dn) * NB + (nr & 63)) * HH + cb;
        }
        if (act) {
            #pragma unroll
            for (int j = 0; j < RPW; ++j) hsT[c][wav * RPW + j] = 0.f;
        }
        const float* gb = Xin + (size_t)row0 * HH;
        #pragma unroll
        for (int j = 0; j < RPW; ++j) px[j] = gb[(size_t)j * HH + cb];   // step 0

        for (int s = 0; s < dn; ++s) {
            // publish this step's x (transposed; wave-owned columns, no barrier)
            if (act) {
                #pragma unroll
                for (int j = 0; j < RPW; ++j) xsT[c][wav * RPW + j] = px[j];
            }
            // prefetch next step's x (lands during the k-loop)
            const int sn = (s + 1 < dn) ? s + 1 : s;
            float nx[RPW];
            #pragma unroll
            for (int j = 0; j < RPW; ++j)
                nx[j] = gb[((size_t)sn * Nbatch + j) * HH + cb];

            float gz[RPW], gr[RPW], gh[RPW], az[RPW], ar[RPW], ah[RPW];
            #pragma unroll
            for (int j = 0; j < RPW; ++j) {
                gz[j] = biz; gr[j] = bir; gh[j] = bih;
                az[j] = brz; ar[j] = brr; ah[j] = brh;
            }
            #pragma unroll 5
            for (int k = 0; k < HH; ++k) {
                float4 uw = *(const float4*)&UWs[k][cb][0];
                float2 w2 = *(const float2*)&W2s[k][cb][0];
                float hv[RPW], xv[RPW];
                if constexpr (RPW == 4) {
                    float4 t  = *(const float4*)&hsT[k][wav * RPW];
                    hv[0] = t.x; hv[1] = t.y; hv[2] = t.z; hv[3] = t.w;
                    float4 u2 = *(const float4*)&xsT[k][wav * RPW];
                    xv[0] = u2.x; xv[1] = u2.y; xv[2] = u2.z; xv[3] = u2.w;
                } else if constexpr (RPW == 2) {
                    float2 t  = *(const float2*)&hsT[k][wav * RPW];
                    hv[0] = t.x; hv[1] = t.y;
                    float2 u2 = *(const float2*)&xsT[k][wav * RPW];
                    xv[0] = u2.x; xv[1] = u2.y;
                } else {
                    hv[0] = hsT[k][wav * RPW];
                    xv[0] = xsT[k][wav * RPW];
                }
                #pragma unroll
                for (int j = 0; j < RPW; ++j) {
                    az[j] += hv[j] * uw.x;
                    ar[j] += hv[j] * uw.y;
                    ah[j] += hv[j] * uw.z;
                    gz[j] += xv[j] * uw.w;
                    gr[j] += xv[j] * w2.x;
                    gh[j] += xv[j] * w2.y;
                }
            }
            #pragma unroll
            for (int j = 0; j < RPW; ++j) {
                float z  = sigm(gz[j] + az[j]);
                float r  = sigm(gr[j] + ar[j]);
                float hh = tanh_f(gh[j] + r * ah[j]);
                float hn = z * h[j] + (1.f - z) * hh;
                h[j] = hn;
                if (act) {
                    hsT[c][wav * RPW + j] = hn;
                    Xout[obase[j] + (size_t)s * NB * HH] = hn;
                }
            }
            #pragma unroll
            for (int j = 0; j < RPW; ++j) px[j] = nx[j];
        }
    }
}

// ---------------- Head: split-K partial GEMM (no bias/relu here) ----------------
__global__ __launch_bounds__(256) void dense2_kernel(
    const float* __restrict__ X,              // [MTOT,50] f32 final layer (time-major)
    const float* __restrict__ W2,             // [1600,1600] f32
    float* __restrict__ part)                 // [16,64,1600] f32 partials
{
    __shared__ float fs[8][100];              // 3.2 KB
    const int tid = threadIdx.x;
    const int c  = blockIdx.x * 256 + tid;
    const int r0 = blockIdx.y * 8;
    const int kz = blockIdx.z;
    for (int i = tid; i < 8 * 100; i += 256) {
        int r = i / 100, fl = i - r * 100;
        int f = kz * 100 + fl, j = f / HH, k = f - j * HH;
        fs[r][fl] = X[((size_t)(TTT - 32 + j) * NB + (r0 + r)) * HH + k];
    }
    __syncthreads();
    if (c < 1600) {
        float a[8] = {0, 0, 0, 0, 0, 0, 0, 0};
        const float* w = W2 + (size_t)kz * 100 * 1600 + c;
        for (int fl = 0; fl < 100; ++fl) {
            float wv = w[(size_t)fl * 1600];
            #pragma unroll
            for (int r = 0; r < 8; ++r) a[r] += fs[r][fl] * wv;
        }
        #pragma unroll
        for (int r = 0; r < 8; ++r)
            part[((size_t)kz * NB + r0 + r) * 1600 + c] = a[r];
    }
}

// ---------------- Classifier: sum partials + bias + relu, then softmax ----------------
__global__ __launch_bounds__(256) void cls_kernel(
    const float* __restrict__ part,           // [16,64,1600] f32 partials
    const float* __restrict__ b2,             // [1600] f32
    const float* __restrict__ Wc,             // [1600,41] f32
    const float* __restrict__ bc,             // [41] f32
    float* __restrict__ out)                  // [64,41] f32
{
    __shared__ float hrow[1600];
    __shared__ float lg[41];
    __shared__ float red[2];
    const int b = blockIdx.x;
    const int t = threadIdx.x;
    for (int i = t; i < 1600; i += 256) {
        float s = b2[i];
        #pragma unroll 4
        for (int kz = 0; kz < 16; ++kz)
            s += part[((size_t)kz * NB + b) * 1600 + i];
        hrow[i] = s > 0.f ? s : 0.f;
    }
    __syncthreads();
    if (t < 41) {
        float acc = bc[t];
        for (int f = 0; f < 1600; ++f) acc += hrow[f] * Wc[f * 41 + t];
        lg[t] = acc;
    }
    __syncthreads();
    if (t == 0) {
        float mx = lg[0];
        for (int i = 1; i < 41; ++i) mx = fmaxf(mx, lg[i]);
        red[0] = mx;
    }
    __syncthreads();
    if (t < 41) lg[t] = expf(lg[t] - red[0]);
    __syncthreads();
    if (t == 0) {
        float sm = 0.f;
        for (int i = 0; i < 41; ++i) sm += lg[i];
        red[1] = 1.f / sm;
    }
    __syncthreads();
    if (t < 41) out[b * 41 + t] = lg[t] * red[1];
}

extern "C" void kernel_launch(void* const* d_in, const int* in_sizes, int n_in,
                              void* d_out, int out_size, void* d_ws, size_t ws_size,
                              hipStream_t stream)
{
    const float* x   = (const float*)d_in[0];    // [64,2048,128]
    const float* W0  = (const float*)d_in[1];    // [128,150]
    const float* U0  = (const float*)d_in[2];    // [50,150]
    const float* b0  = (const float*)d_in[3];    // [2,150]
    const float* Ws  = (const float*)d_in[4];    // [5,50,150]
    const float* Us  = (const float*)d_in[5];    // [5,50,150]
    const float* bs  = (const float*)d_in[6];    // [5,2,150]
    const float* W2  = (const float*)d_in[7];    // [1600,1600]
    const float* b2  = (const float*)d_in[8];    // [1600]
    const float* Wc  = (const float*)d_in[9];    // [1600,41]
    const float* bc  = (const float*)d_in[10];   // [41]

    // R9/R12 workspace layout:
    //   region1 = MTOT*XGS floats: xg (layer 0) -> bufB (layers 1..5)
    //             part at region1 + MTOT*HH (disjoint from bufB)
    //   bufA    = MTOT*HH floats after region1
    float* region1 = (float*)d_ws;
    float* xg   = region1;
    float* bufB = region1;
    float* part = region1 + (size_t)MTOT * HH;
    float* bufA = region1 + (size_t)MTOT * XGS;

    static const int rates[6] = {32, 64, 128, 256, 512, 1024};

    // ---- layer 0: GEMM proj + gru_reg <4,1> (R5 config: 2048 waves = 2/SIMD) ----
    proj0_kernel<<<dim3(MTOT / 128, 5), 256, 0, stream>>>(x, W0, b0, xg);
    {
        int dn = TTT / rates[0], Nbatch = rates[0] * NB;   // 64, 2048
        int ngroups = Nbatch / 4;                          // R=4 for <4,1>
        int grid = ngroups < 512 ? ngroups : 512;
        gru_reg<4, 1><<<grid, 256, 0, stream>>>(xg, U0, b0, bufA, dn, Nbatch, ngroups);
    }

    // ---- layers 1..5: fused2 WPB=8, RPW so total waves >= 4096 (4/SIMD) ----
    const float* cur = bufA;
    for (int l = 1; l < 6; ++l) {
        const float* Wl = Ws + (size_t)(l - 1) * HH * GG;
        const float* Ul = Us + (size_t)(l - 1) * HH * GG;
        const float* bl = bs + (size_t)(l - 1) * 2 * GG;
        int rate = rates[l];
        int Nbatch = rate * NB;
        int dn = TTT / rate;
        float* dst = (cur == bufA) ? bufB : bufA;
        if (l == 1) {                                      // Nbatch=4096: RPW=1, R=8
            int ngroups = Nbatch / 8;                      // 512 blocks = 2/CU
            int grid = ngroups < 512 ? ngroups : 512;
            gru_fused2<8, 1><<<grid, 512, 0, stream>>>(cur, Wl, Ul, bl, dst, dn, Nbatch, ngroups);
        } else if (l == 2) {                               // Nbatch=8192: RPW=2, R=16
            int ngroups = Nbatch / 16;                     // 512 blocks
            int grid = ngroups < 512 ? ngroups : 512;
            gru_fused2<8, 2><<<grid, 512, 0, stream>>>(cur, Wl, Ul, bl, dst, dn, Nbatch, ngroups);
        } else {                                           // Nbatch>=16384: RPW=4, R=32
            int ngroups = Nbatch / 32;                     // >=512 blocks
            int grid = ngroups < 512 ? ngroups : 512;
            gru_fused2<8, 4><<<grid, 512, 0, stream>>>(cur, Wl, Ul, bl, dst, dn, Nbatch, ngroups);
        }
        cur = dst;
    }
    // ping-pong A->B->A->B->A->B: final cur = bufB (disjoint from part)

    // head: split-K dense2 into partials, reduce+relu inside cls
    dense2_kernel<<<dim3(7, 8, 16), 256, 0, stream>>>(cur, W2, part);
    cls_kernel<<<NB, 256, 0, stream>>>(part, b2, Wc, bc, (float*)d_out);
}

// Round 14
// 896.560 us; speedup vs baseline: 1.0446x; 1.0446x over previous
//
#include <hip/hip_runtime.h>
#include <math.h>

// Dims (fixed by the problem)
#define HH   50          // hidden
#define GG   150         // 3H
#define XGS  152         // xg row stride (padded)
#define TTT  2048        // T
#define NB   64          // batch B
#define MTOT (TTT*NB)    // 131072 rows per layer
#define D0   128         // layer-0 input dim

static __device__ __forceinline__ float sigm(float x) {
    return 1.f / (1.f + __expf(-x));
}
static __device__ __forceinline__ float tanh_f(float x) {
    return 1.f - 2.f / (__expf(2.f * x) + 1.f);   // saturates correctly at +/-inf
}

static __device__ __forceinline__ void fma4(float4& a, float s, const float4& w) {
    a.x += s * w.x; a.y += s * w.y; a.z += s * w.z; a.w += s * w.w;
}

static __device__ __forceinline__ float bcast(float v, int k) {
    return __uint_as_float(__builtin_amdgcn_readlane(__float_as_uint(v), k));
}

// ---------------- Layer-0 input projection: Xg = X0 @ W + bi ----------------
// (proven, ~110 us)
__global__ __launch_bounds__(256) void proj0_kernel(
    const float* __restrict__ x,              // [64,2048,128] f32
    const float* __restrict__ W,              // [128,150] f32
    const float* __restrict__ bias,           // [2,150] f32 (bi = bias[0])
    float* __restrict__ xg)                   // [MTOT,XGS] f32
{
    __shared__ float xs[128][36];             // k-quarter of x, stride 36 (18.4 KB)
    __shared__ float Wp[32][32];              // k-quarter of W cols for this tile (4 KB)
    const int tid  = threadIdx.x;
    const int m0   = blockIdx.x * 128;
    const int c0   = blockIdx.y * 32;         // col-tile base: 0,32,64,96,128
    const int rowq = tid >> 3;                // 0..31
    const int colq = tid & 7;                 // 0..7

    float4 acc[4];
    #pragma unroll
    for (int j = 0; j < 4; ++j) acc[j] = make_float4(0.f, 0.f, 0.f, 0.f);

    for (int q = 0; q < 4; ++q) {             // K quarters of 32
        if (q) __syncthreads();
        for (int i = tid; i < 128 * 8; i += 256) {
            int r = i >> 3, k4 = (i & 7) * 4;
            int row = m0 + r, t = row >> 6, b = row & 63;
            *(float4*)&xs[r][k4] =
                *(const float4*)&x[((size_t)b * TTT + t) * D0 + q * 32 + k4];
        }
        for (int i = tid; i < 32 * 32; i += 256) {
            int k = i >> 5, c = i & 31, gc = c0 + c;
            Wp[k][c] = (gc < GG) ? W[(q * 32 + k) * GG + gc] : 0.f;
        }
        __syncthreads();
        const float* xr0 = xs[rowq * 4 + 0];
        const float* xr1 = xs[rowq * 4 + 1];
        const float* xr2 = xs[rowq * 4 + 2];
        const float* xr3 = xs[rowq * 4 + 3];
        for (int k = 0; k < 32; k += 4) {
            float4 w0 = *(const float4*)&Wp[k + 0][colq * 4];
            float4 w1 = *(const float4*)&Wp[k + 1][colq * 4];
            float4 w2 = *(const float4*)&Wp[k + 2][colq * 4];
            float4 w3 = *(const float4*)&Wp[k + 3][colq * 4];
            float4 x0 = *(const float4*)&xr0[k];
            float4 x1 = *(const float4*)&xr1[k];
            float4 x2 = *(const float4*)&xr2[k];
            float4 x3 = *(const float4*)&xr3[k];
            fma4(acc[0], x0.x, w0); fma4(acc[0], x0.y, w1);
            fma4(acc[0], x0.z, w2); fma4(acc[0], x0.w, w3);
            fma4(acc[1], x1.x, w0); fma4(acc[1], x1.y, w1);
            fma4(acc[1], x1.z, w2); fma4(acc[1], x1.w, w3);
            fma4(acc[2], x2.x, w0); fma4(acc[2], x2.y, w1);
            fma4(acc[2], x2.z, w2); fma4(acc[2], x2.w, w3);
            fma4(acc[3], x3.x, w0); fma4(acc[3], x3.y, w1);
            fma4(acc[3], x3.z, w2); fma4(acc[3], x3.w, w3);
        }
    }
    const int cc = c0 + colq * 4;
    if (cc <= XGS - 4) {                      // cc <= 148; cols 150/151 unread pad
        float4 bv = *(const float4*)&bias[cc];
        #pragma unroll
        for (int j = 0; j < 4; ++j) {
            float4 o;
            o.x = acc[j].x + bv.x; o.y = acc[j].y + bv.y;
            o.z = acc[j].z + bv.z; o.w = acc[j].w + bv.w;
            *(float4*)&xg[(size_t)(m0 + rowq * 4 + j) * XGS + cc] = o;
        }
    }
}

// ---------------- Layer-0 GRU: h in registers, readlane broadcast ----------------
// <4,1>: 2048 waves = 2/SIMD (R5-measured ~115 us; <4,2> regresses to 139).
template<int WPB, int RPW>
__global__ __launch_bounds__(WPB * 64) void gru_reg(
    const float* __restrict__ xg,             // [dn*Nbatch, XGS] f32 (includes bi)
    const float* __restrict__ U,              // [50,150] f32
    const float* __restrict__ bias,           // [2,150] f32 (br = bias+150)
    float* __restrict__ Xout,                 // [MTOT,50] f32 time-major
    int dn, int Nbatch, int ngroups)
{
    constexpr int R = WPB * RPW;              // rows per block per group
    __shared__ __align__(16) float Ut[HH][HH][4];   // [k][unit][{z,r,h,0}] 40 KB

    const int tid  = threadIdx.x;
    const int wav  = tid >> 6;
    const int lane = tid & 63;

    for (int i = tid; i < HH * HH; i += WPB * 64)
        Ut[i / HH][i - (i / HH) * HH][3] = 0.f;
    for (int i = tid; i < HH * GG; i += WPB * 64) {
        int k = i / GG, cc = i - k * GG;
        Ut[k][cc % HH][cc / HH] = U[i];       // U cols: [z|r|h] blocks of 50
    }
    __syncthreads();                          // the only block-wide barrier

    const int c  = lane;
    const int cb = (c < HH) ? c : HH - 1;     // clamped for loads (lanes 50..63)

    const float bz  = bias[GG + cb];
    const float brr = bias[GG + HH + cb];
    const float bh  = bias[GG + 2 * HH + cb];

    for (int grp = blockIdx.x; grp < ngroups; grp += gridDim.x) {
        const int row0 = grp * R + wav * RPW;
        float h[RPW];
        #pragma unroll
        for (int j = 0; j < RPW; ++j) h[j] = 0.f;
        size_t obase[RPW];
        #pragma unroll
        for (int j = 0; j < RPW; ++j) {
            int nr = row0 + j;
            obase[j] = ((size_t)((nr >> 6) * dn) * NB + (nr & 63)) * HH + cb;
        }
        const float* gb = xg + (size_t)row0 * XGS;

        float px[RPW], pr[RPW], ph[RPW];
        #pragma unroll
        for (int j = 0; j < RPW; ++j) {       // preload step 0
            const float* g = gb + (size_t)j * XGS;
            px[j] = g[cb]; pr[j] = g[HH + cb]; ph[j] = g[2 * HH + cb];
        }

        for (int s = 0; s < dn; ++s) {
            const int sn = (s + 1 < dn) ? s + 1 : s;
            float nx[RPW], nrr[RPW], nh[RPW];
            #pragma unroll
            for (int j = 0; j < RPW; ++j) {
                const float* g = gb + ((size_t)sn * Nbatch + j) * XGS;
                nx[j] = g[cb]; nrr[j] = g[HH + cb]; nh[j] = g[2 * HH + cb];
            }
            float az[RPW], ar[RPW], ah[RPW];
            #pragma unroll
            for (int j = 0; j < RPW; ++j) { az[j] = bz; ar[j] = brr; ah[j] = bh; }
            #pragma unroll 5
            for (int k = 0; k < HH; ++k) {
                float4 w = *(const float4*)&Ut[k][c < HH ? c : 0][0];
                #pragma unroll
                for (int j = 0; j < RPW; ++j) {
                    float hk = bcast(h[j], k);
                    az[j] += hk * w.x;
                    ar[j] += hk * w.y;
                    ah[j] += hk * w.z;
                }
            }
            #pragma unroll
            for (int j = 0; j < RPW; ++j) {
                float z  = sigm(px[j] + az[j]);
                float r  = sigm(pr[j] + ar[j]);
                float hh = tanh_f(ph[j] + r * ah[j]);
                float hn = z * h[j] + (1.f - z) * hh;
                h[j] = hn;
                if (c < HH) Xout[obase[j] + (size_t)s * NB * HH] = hn;
            }
            #pragma unroll
            for (int j = 0; j < RPW; ++j) { px[j] = nx[j]; pr[j] = nrr[j]; ph[j] = nh[j]; }
        }
    }
}

// ---------------- Fused proj+GRU v2: LDS-broadcast h/x, packed weights ----------------
// R12-proven mechanism. R13 established the cost model: LDS-unit-throughput
// bound, time ~ 50 k-iters x ~26 LDS-cy x (MTOT/RPW/256 per CU) -> ~70us floor
// at RPW=4, halving with RPW; occupancy >=2/SIMD is sufficient (4/SIMD gave
// 0%). So: RPW as high as waves>=2048 allows. RPW=8 path added for L3-5.
template<int WPB, int RPW>
__global__ __launch_bounds__(WPB * 64) void gru_fused2(
    const float* __restrict__ Xin,            // [dn*Nbatch, HH] f32 (prev layer)
    const float* __restrict__ W,              // [50,150] f32
    const float* __restrict__ U,              // [50,150] f32
    const float* __restrict__ bias,           // [2,150] f32
    float* __restrict__ Xout,                 // [MTOT,50] f32 time-major
    int dn, int Nbatch, int ngroups)
{
    constexpr int R  = WPB * RPW;             // rows per block per group
    constexpr int RS = R + 4;                 // padded row stride (16B-aligned)
    __shared__ __align__(16) float UWs[HH][HH][4];  // {Uz,Ur,Uh,Wz} 40 KB
    __shared__ __align__(16) float W2s[HH][HH][2];  // {Wr,Wh}       20 KB
    __shared__ __align__(16) float hsT[HH][RS];     // h state, [unit][col]
    __shared__ __align__(16) float xsT[HH][RS];     // x of current step

    const int tid  = threadIdx.x;
    const int wav  = tid >> 6;
    const int lane = tid & 63;

    for (int i = tid; i < HH * HH; i += WPB * 64) {
        int k = i / HH, cc = i - k * HH;
        const float* u = U + k * GG;
        const float* w = W + k * GG;
        UWs[k][cc][0] = u[cc];
        UWs[k][cc][1] = u[HH + cc];
        UWs[k][cc][2] = u[2 * HH + cc];
        UWs[k][cc][3] = w[cc];
        W2s[k][cc][0] = w[HH + cc];
        W2s[k][cc][1] = w[2 * HH + cc];
    }
    __syncthreads();                          // the only block-wide barrier

    const int c   = lane;
    const int cb  = (c < HH) ? c : HH - 1;
    const bool act = (c < HH);

    const float biz = bias[cb];
    const float bir = bias[HH + cb];
    const float bih = bias[2 * HH + cb];
    const float brz = bias[GG + cb];
    const float brr = bias[GG + HH + cb];
    const float brh = bias[GG + 2 * HH + cb];

    for (int grp = blockIdx.x; grp < ngroups; grp += gridDim.x) {
        const int row0 = grp * R + wav * RPW;
        float h[RPW], px[RPW];
        size_t obase[RPW];
        #pragma unroll
        for (int j = 0; j < RPW; ++j) {
            h[j] = 0.f;
            int nr = row0 + j;
            obase[j] = ((size_t)((nr >> 6) * dn) * NB + (nr & 63)) * HH + cb;
        }
        if (act) {
            #pragma unroll
            for (int j = 0; j < RPW; ++j) hsT[c][wav * RPW + j] = 0.f;
        }
        const float* gb = Xin + (size_t)row0 * HH;
        #pragma unroll
        for (int j = 0; j < RPW; ++j) px[j] = gb[(size_t)j * HH + cb];   // step 0

        for (int s = 0; s < dn; ++s) {
            // publish this step's x (transposed; wave-owned columns, no barrier)
            if (act) {
                #pragma unroll
                for (int j = 0; j < RPW; ++j) xsT[c][wav * RPW + j] = px[j];
            }
            // prefetch next step's x (lands during the k-loop)
            const int sn = (s + 1 < dn) ? s + 1 : s;
            float nx[RPW];
            #pragma unroll
            for (int j = 0; j < RPW; ++j)
                nx[j] = gb[((size_t)sn * Nbatch + j) * HH + cb];

            float gz[RPW], gr[RPW], gh[RPW], az[RPW], ar[RPW], ah[RPW];
            #pragma unroll
            for (int j = 0; j < RPW; ++j) {
                gz[j] = biz; gr[j] = bir; gh[j] = bih;
                az[j] = brz; ar[j] = brr; ah[j] = brh;
            }
            #pragma unroll 5
            for (int k = 0; k < HH; ++k) {
                float4 uw = *(const float4*)&UWs[k][cb][0];
                float2 w2 = *(const float2*)&W2s[k][cb][0];
                float hv[RPW], xv[RPW];
                if constexpr (RPW == 8) {
                    float4 t0 = *(const float4*)&hsT[k][wav * RPW];
                    float4 t1 = *(const float4*)&hsT[k][wav * RPW + 4];
                    hv[0] = t0.x; hv[1] = t0.y; hv[2] = t0.z; hv[3] = t0.w;
                    hv[4] = t1.x; hv[5] = t1.y; hv[6] = t1.z; hv[7] = t1.w;
                    float4 u0 = *(const float4*)&xsT[k][wav * RPW];
                    float4 u1 = *(const float4*)&xsT[k][wav * RPW + 4];
                    xv[0] = u0.x; xv[1] = u0.y; xv[2] = u0.z; xv[3] = u0.w;
                    xv[4] = u1.x; xv[5] = u1.y; xv[6] = u1.z; xv[7] = u1.w;
                } else if constexpr (RPW == 4) {
                    float4 t  = *(const float4*)&hsT[k][wav * RPW];
                    hv[0] = t.x; hv[1] = t.y; hv[2] = t.z; hv[3] = t.w;
                    float4 u2 = *(const float4*)&xsT[k][wav * RPW];
                    xv[0] = u2.x; xv[1] = u2.y; xv[2] = u2.z; xv[3] = u2.w;
                } else if constexpr (RPW == 2) {
                    float2 t  = *(const float2*)&hsT[k][wav * RPW];
                    hv[0] = t.x; hv[1] = t.y;
                    float2 u2 = *(const float2*)&xsT[k][wav * RPW];
                    xv[0] = u2.x; xv[1] = u2.y;
                } else {
                    hv[0] = hsT[k][wav * RPW];
                    xv[0] = xsT[k][wav * RPW];
                }
                #pragma unroll
                for (int j = 0; j < RPW; ++j) {
                    az[j] += hv[j] * uw.x;
                    ar[j] += hv[j] * uw.y;
                    ah[j] += hv[j] * uw.z;
                    gz[j] += xv[j] * uw.w;
                    gr[j] += xv[j] * w2.x;
                    gh[j] += xv[j] * w2.y;
                }
            }
            #pragma unroll
            for (int j = 0; j < RPW; ++j) {
                float z  = sigm(gz[j] + az[j]);
                float r  = sigm(gr[j] + ar[j]);
                float hh = tanh_f(gh[j] + r * ah[j]);
                float hn = z * h[j] + (1.f - z) * hh;
                h[j] = hn;
                if (act) {
                    hsT[c][wav * RPW + j] = hn;
                    Xout[obase[j] + (size_t)s * NB * HH] = hn;
                }
            }
            #pragma unroll
            for (int j = 0; j < RPW; ++j) px[j] = nx[j];
        }
    }
}

// ---------------- Head: split-K partial GEMM (no bias/relu here) ----------------
__global__ __launch_bounds__(256) void dense2_kernel(
    const float* __restrict__ X,              // [MTOT,50] f32 final layer (time-major)
    const float* __restrict__ W2,             // [1600,1600] f32
    float* __restrict__ part)                 // [16,64,1600] f32 partials
{
    __shared__ float fs[8][100];              // 3.2 KB
    const int tid = threadIdx.x;
    const int c  = blockIdx.x * 256 + tid;
    const int r0 = blockIdx.y * 8;
    const int kz = blockIdx.z;
    for (int i = tid; i < 8 * 100; i += 256) {
        int r = i / 100, fl = i - r * 100;
        int f = kz * 100 + fl, j = f / HH, k = f - j * HH;
        fs[r][fl] = X[((size_t)(TTT - 32 + j) * NB + (r0 + r)) * HH + k];
    }
    __syncthreads();
    if (c < 1600) {
        float a[8] = {0, 0, 0, 0, 0, 0, 0, 0};
        const float* w = W2 + (size_t)kz * 100 * 1600 + c;
        for (int fl = 0; fl < 100; ++fl) {
            float wv = w[(size_t)fl * 1600];
            #pragma unroll
            for (int r = 0; r < 8; ++r) a[r] += fs[r][fl] * wv;
        }
        #pragma unroll
        for (int r = 0; r < 8; ++r)
            part[((size_t)kz * NB + r0 + r) * 1600 + c] = a[r];
    }
}

// ---------------- Classifier: sum partials + bias + relu, then softmax ----------------
__global__ __launch_bounds__(256) void cls_kernel(
    const float* __restrict__ part,           // [16,64,1600] f32 partials
    const float* __restrict__ b2,             // [1600] f32
    const float* __restrict__ Wc,             // [1600,41] f32
    const float* __restrict__ bc,             // [41] f32
    float* __restrict__ out)                  // [64,41] f32
{
    __shared__ float hrow[1600];
    __shared__ float lg[41];
    __shared__ float red[2];
    const int b = blockIdx.x;
    const int t = threadIdx.x;
    for (int i = t; i < 1600; i += 256) {
        float s = b2[i];
        #pragma unroll 4
        for (int kz = 0; kz < 16; ++kz)
            s += part[((size_t)kz * NB + b) * 1600 + i];
        hrow[i] = s > 0.f ? s : 0.f;
    }
    __syncthreads();
    if (t < 41) {
        float acc = bc[t];
        for (int f = 0; f < 1600; ++f) acc += hrow[f] * Wc[f * 41 + t];
        lg[t] = acc;
    }
    __syncthreads();
    if (t == 0) {
        float mx = lg[0];
        for (int i = 1; i < 41; ++i) mx = fmaxf(mx, lg[i]);
        red[0] = mx;
    }
    __syncthreads();
    if (t < 41) lg[t] = expf(lg[t] - red[0]);
    __syncthreads();
    if (t == 0) {
        float sm = 0.f;
        for (int i = 0; i < 41; ++i) sm += lg[i];
        red[1] = 1.f / sm;
    }
    __syncthreads();
    if (t < 41) out[b * 41 + t] = lg[t] * red[1];
}

extern "C" void kernel_launch(void* const* d_in, const int* in_sizes, int n_in,
                              void* d_out, int out_size, void* d_ws, size_t ws_size,
                              hipStream_t stream)
{
    const float* x   = (const float*)d_in[0];    // [64,2048,128]
    const float* W0  = (const float*)d_in[1];    // [128,150]
    const float* U0  = (const float*)d_in[2];    // [50,150]
    const float* b0  = (const float*)d_in[3];    // [2,150]
    const float* Ws  = (const float*)d_in[4];    // [5,50,150]
    const float* Us  = (const float*)d_in[5];    // [5,50,150]
    const float* bs  = (const float*)d_in[6];    // [5,2,150]
    const float* W2  = (const float*)d_in[7];    // [1600,1600]
    const float* b2  = (const float*)d_in[8];    // [1600]
    const float* Wc  = (const float*)d_in[9];    // [1600,41]
    const float* bc  = (const float*)d_in[10];   // [41]

    // R9/R12 workspace layout:
    //   region1 = MTOT*XGS floats: xg (layer 0) -> bufB (layers 1..5)
    //             part at region1 + MTOT*HH (disjoint from bufB)
    //   bufA    = MTOT*HH floats after region1
    float* region1 = (float*)d_ws;
    float* xg   = region1;
    float* bufB = region1;
    float* part = region1 + (size_t)MTOT * HH;
    float* bufA = region1 + (size_t)MTOT * XGS;

    static const int rates[6] = {32, 64, 128, 256, 512, 1024};

    // ---- layer 0: GEMM proj + gru_reg <4,1> (2048 waves = 2/SIMD, ~115 us) ----
    proj0_kernel<<<dim3(MTOT / 128, 5), 256, 0, stream>>>(x, W0, b0, xg);
    {
        int dn = TTT / rates[0], Nbatch = rates[0] * NB;   // 64, 2048
        int ngroups = Nbatch / 4;                          // R=4 for <4,1>
        int grid = ngroups < 512 ? ngroups : 512;
        gru_reg<4, 1><<<grid, 256, 0, stream>>>(xg, U0, b0, bufA, dn, Nbatch, ngroups);
    }

    // ---- layers 1..5: fused2, RPW = max with waves >= 2048 (2/SIMD) ----
    const float* cur = bufA;
    for (int l = 1; l < 6; ++l) {
        const float* Wl = Ws + (size_t)(l - 1) * HH * GG;
        const float* Ul = Us + (size_t)(l - 1) * HH * GG;
        const float* bl = bs + (size_t)(l - 1) * 2 * GG;
        int rate = rates[l];
        int Nbatch = rate * NB;
        int dn = TTT / rate;
        float* dst = (cur == bufA) ? bufB : bufA;
        if (l == 1) {                                      // Nbatch=4096: RPW=2 (2048 waves)
            int ngroups = Nbatch / 8;
            int grid = ngroups < 512 ? ngroups : 512;
            gru_fused2<4, 2><<<grid, 256, 0, stream>>>(cur, Wl, Ul, bl, dst, dn, Nbatch, ngroups);
        } else if (l == 2) {                               // Nbatch=8192: RPW=4 (2048 waves)
            int ngroups = Nbatch / 16;
            int grid = ngroups < 512 ? ngroups : 512;
            gru_fused2<4, 4><<<grid, 256, 0, stream>>>(cur, Wl, Ul, bl, dst, dn, Nbatch, ngroups);
        } else {                                           // Nbatch>=16384: RPW=8 (>=2048 waves)
            int ngroups = Nbatch / 32;
            int grid = ngroups < 512 ? ngroups : 512;
            gru_fused2<4, 8><<<grid, 256, 0, stream>>>(cur, Wl, Ul, bl, dst, dn, Nbatch, ngroups);
        }
        cur = dst;
    }
    // ping-pong A->B->A->B->A->B: final cur = bufB (disjoint from part)

    // head: split-K dense2 into partials, reduce+relu inside cls
    dense2_kernel<<<dim3(7, 8, 16), 256, 0, stream>>>(cur, W2, part);
    cls_kernel<<<NB, 256, 0, stream>>>(part, b2, Wc, bc, (float*)d_out);
}

// Round 15
// 880.300 us; speedup vs baseline: 1.0639x; 1.0185x over previous
//
#include <hip/hip_runtime.h>
#include <math.h>

// Dims (fixed by the problem)
#define HH   50          // hidden
#define GG   150         // 3H
#define XGS  152         // xg row stride (padded)
#define TTT  2048        // T
#define NB   64          // batch B
#define MTOT (TTT*NB)    // 131072 rows per layer
#define D0   128         // layer-0 input dim

static __device__ __forceinline__ float sigm(float x) {
    return 1.f / (1.f + __expf(-x));
}
static __device__ __forceinline__ float tanh_f(float x) {
    return 1.f - 2.f / (__expf(2.f * x) + 1.f);   // saturates correctly at +/-inf
}

static __device__ __forceinline__ void fma4(float4& a, float s, const float4& w) {
    a.x += s * w.x; a.y += s * w.y; a.z += s * w.z; a.w += s * w.w;
}

static __device__ __forceinline__ float bcast(float v, int k) {
    return __uint_as_float(__builtin_amdgcn_readlane(__float_as_uint(v), k));
}

// ---------------- Layer-0 input projection: Xg = X0 @ W + bi ----------------
// (proven, ~110 us)
__global__ __launch_bounds__(256) void proj0_kernel(
    const float* __restrict__ x,              // [64,2048,128] f32
    const float* __restrict__ W,              // [128,150] f32
    const float* __restrict__ bias,           // [2,150] f32 (bi = bias[0])
    float* __restrict__ xg)                   // [MTOT,XGS] f32
{
    __shared__ float xs[128][36];             // k-quarter of x, stride 36 (18.4 KB)
    __shared__ float Wp[32][32];              // k-quarter of W cols for this tile (4 KB)
    const int tid  = threadIdx.x;
    const int m0   = blockIdx.x * 128;
    const int c0   = blockIdx.y * 32;         // col-tile base: 0,32,64,96,128
    const int rowq = tid >> 3;                // 0..31
    const int colq = tid & 7;                 // 0..7

    float4 acc[4];
    #pragma unroll
    for (int j = 0; j < 4; ++j) acc[j] = make_float4(0.f, 0.f, 0.f, 0.f);

    for (int q = 0; q < 4; ++q) {             // K quarters of 32
        if (q) __syncthreads();
        for (int i = tid; i < 128 * 8; i += 256) {
            int r = i >> 3, k4 = (i & 7) * 4;
            int row = m0 + r, t = row >> 6, b = row & 63;
            *(float4*)&xs[r][k4] =
                *(const float4*)&x[((size_t)b * TTT + t) * D0 + q * 32 + k4];
        }
        for (int i = tid; i < 32 * 32; i += 256) {
            int k = i >> 5, c = i & 31, gc = c0 + c;
            Wp[k][c] = (gc < GG) ? W[(q * 32 + k) * GG + gc] : 0.f;
        }
        __syncthreads();
        const float* xr0 = xs[rowq * 4 + 0];
        const float* xr1 = xs[rowq * 4 + 1];
        const float* xr2 = xs[rowq * 4 + 2];
        const float* xr3 = xs[rowq * 4 + 3];
        for (int k = 0; k < 32; k += 4) {
            float4 w0 = *(const float4*)&Wp[k + 0][colq * 4];
            float4 w1 = *(const float4*)&Wp[k + 1][colq * 4];
            float4 w2 = *(const float4*)&Wp[k + 2][colq * 4];
            float4 w3 = *(const float4*)&Wp[k + 3][colq * 4];
            float4 x0 = *(const float4*)&xr0[k];
            float4 x1 = *(const float4*)&xr1[k];
            float4 x2 = *(const float4*)&xr2[k];
            float4 x3 = *(const float4*)&xr3[k];
            fma4(acc[0], x0.x, w0); fma4(acc[0], x0.y, w1);
            fma4(acc[0], x0.z, w2); fma4(acc[0], x0.w, w3);
            fma4(acc[1], x1.x, w0); fma4(acc[1], x1.y, w1);
            fma4(acc[1], x1.z, w2); fma4(acc[1], x1.w, w3);
            fma4(acc[2], x2.x, w0); fma4(acc[2], x2.y, w1);
            fma4(acc[2], x2.z, w2); fma4(acc[2], x2.w, w3);
            fma4(acc[3], x3.x, w0); fma4(acc[3], x3.y, w1);
            fma4(acc[3], x3.z, w2); fma4(acc[3], x3.w, w3);
        }
    }
    const int cc = c0 + colq * 4;
    if (cc <= XGS - 4) {                      // cc <= 148; cols 150/151 unread pad
        float4 bv = *(const float4*)&bias[cc];
        #pragma unroll
        for (int j = 0; j < 4; ++j) {
            float4 o;
            o.x = acc[j].x + bv.x; o.y = acc[j].y + bv.y;
            o.z = acc[j].z + bv.z; o.w = acc[j].w + bv.w;
            *(float4*)&xg[(size_t)(m0 + rowq * 4 + j) * XGS + cc] = o;
        }
    }
}

// ---------------- Layer-0 GRU: h in registers, readlane broadcast ----------------
// R5-exact: FULL k-loop unroll. At RPW=1 the per-k footprint (4 VGPR) is
// small enough that deep load-hoisting doesn't spill (R5 measured fast, no
// spill), and the deep in-flight window hides LDS latency at 2 waves/SIMD.
// (R14's `unroll 5` here cost +44 us: 154 vs R5's ~110.)
template<int WPB, int RPW>
__global__ __launch_bounds__(WPB * 64) void gru_reg(
    const float* __restrict__ xg,             // [dn*Nbatch, XGS] f32 (includes bi)
    const float* __restrict__ U,              // [50,150] f32
    const float* __restrict__ bias,           // [2,150] f32 (br = bias+150)
    float* __restrict__ Xout,                 // [MTOT,50] f32 time-major
    int dn, int Nbatch, int ngroups)
{
    constexpr int R = WPB * RPW;              // rows per block per group
    __shared__ __align__(16) float Ut[HH][HH][4];   // [k][unit][{z,r,h,0}] 40 KB

    const int tid  = threadIdx.x;
    const int wav  = tid >> 6;
    const int lane = tid & 63;

    for (int i = tid; i < HH * HH; i += WPB * 64)
        Ut[i / HH][i - (i / HH) * HH][3] = 0.f;
    for (int i = tid; i < HH * GG; i += WPB * 64) {
        int k = i / GG, cc = i - k * GG;
        Ut[k][cc % HH][cc / HH] = U[i];       // U cols: [z|r|h] blocks of 50
    }
    __syncthreads();                          // the only block-wide barrier

    const int c  = lane;
    const int cb = (c < HH) ? c : HH - 1;     // clamped for loads (lanes 50..63)

    const float bz  = bias[GG + cb];
    const float brr = bias[GG + HH + cb];
    const float bh  = bias[GG + 2 * HH + cb];

    for (int grp = blockIdx.x; grp < ngroups; grp += gridDim.x) {
        const int row0 = grp * R + wav * RPW;
        float h[RPW];
        #pragma unroll
        for (int j = 0; j < RPW; ++j) h[j] = 0.f;
        size_t obase[RPW];
        #pragma unroll
        for (int j = 0; j < RPW; ++j) {
            int nr = row0 + j;
            obase[j] = ((size_t)((nr >> 6) * dn) * NB + (nr & 63)) * HH + cb;
        }
        const float* gb = xg + (size_t)row0 * XGS;

        float px[RPW], pr[RPW], ph[RPW];
        #pragma unroll
        for (int j = 0; j < RPW; ++j) {       // preload step 0
            const float* g = gb + (size_t)j * XGS;
            px[j] = g[cb]; pr[j] = g[HH + cb]; ph[j] = g[2 * HH + cb];
        }

        for (int s = 0; s < dn; ++s) {
            const int sn = (s + 1 < dn) ? s + 1 : s;
            float nx[RPW], nrr[RPW], nh[RPW];
            #pragma unroll
            for (int j = 0; j < RPW; ++j) {
                const float* g = gb + ((size_t)sn * Nbatch + j) * XGS;
                nx[j] = g[cb]; nrr[j] = g[HH + cb]; nh[j] = g[2 * HH + cb];
            }
            float az[RPW], ar[RPW], ah[RPW];
            #pragma unroll
            for (int j = 0; j < RPW; ++j) { az[j] = bz; ar[j] = brr; ah[j] = bh; }
            #pragma unroll
            for (int k = 0; k < HH; ++k) {
                float4 w = *(const float4*)&Ut[k][c < HH ? c : 0][0];
                #pragma unroll
                for (int j = 0; j < RPW; ++j) {
                    float hk = bcast(h[j], k);
                    az[j] += hk * w.x;
                    ar[j] += hk * w.y;
                    ah[j] += hk * w.z;
                }
            }
            #pragma unroll
            for (int j = 0; j < RPW; ++j) {
                float z  = sigm(px[j] + az[j]);
                float r  = sigm(pr[j] + ar[j]);
                float hh = tanh_f(ph[j] + r * ah[j]);
                float hn = z * h[j] + (1.f - z) * hh;
                h[j] = hn;
                if (c < HH) Xout[obase[j] + (size_t)s * NB * HH] = hn;
            }
            #pragma unroll
            for (int j = 0; j < RPW; ++j) { px[j] = nx[j]; pr[j] = nrr[j]; ph[j] = nh[j]; }
        }
    }
}

// ---------------- Fused proj+GRU v2: LDS-broadcast h/x, packed weights ----------------
// R12-proven mechanism. Cost model (R13/R14): per-k LDS instr = 2 weight reads
// + ceil(RPW/4)x2 state broadcasts; per-row cost ~ A + B/RPW with A the
// VALU/latency floor. Measured VGPR at unroll 5 was only 52 (cliff at 256) ->
// `unroll 10` doubles the in-flight load window for latency hiding.
template<int WPB, int RPW>
__global__ __launch_bounds__(WPB * 64) void gru_fused2(
    const float* __restrict__ Xin,            // [dn*Nbatch, HH] f32 (prev layer)
    const float* __restrict__ W,              // [50,150] f32
    const float* __restrict__ U,              // [50,150] f32
    const float* __restrict__ bias,           // [2,150] f32
    float* __restrict__ Xout,                 // [MTOT,50] f32 time-major
    int dn, int Nbatch, int ngroups)
{
    constexpr int R  = WPB * RPW;             // rows per block per group
    constexpr int RS = R + 4;                 // padded row stride (16B-aligned)
    __shared__ __align__(16) float UWs[HH][HH][4];  // {Uz,Ur,Uh,Wz} 40 KB
    __shared__ __align__(16) float W2s[HH][HH][2];  // {Wr,Wh}       20 KB
    __shared__ __align__(16) float hsT[HH][RS];     // h state, [unit][col]
    __shared__ __align__(16) float xsT[HH][RS];     // x of current step

    const int tid  = threadIdx.x;
    const int wav  = tid >> 6;
    const int lane = tid & 63;

    for (int i = tid; i < HH * HH; i += WPB * 64) {
        int k = i / HH, cc = i - k * HH;
        const float* u = U + k * GG;
        const float* w = W + k * GG;
        UWs[k][cc][0] = u[cc];
        UWs[k][cc][1] = u[HH + cc];
        UWs[k][cc][2] = u[2 * HH + cc];
        UWs[k][cc][3] = w[cc];
        W2s[k][cc][0] = w[HH + cc];
        W2s[k][cc][1] = w[2 * HH + cc];
    }
    __syncthreads();                          // the only block-wide barrier

    const int c   = lane;
    const int cb  = (c < HH) ? c : HH - 1;
    const bool act = (c < HH);

    const float biz = bias[cb];
    const float bir = bias[HH + cb];
    const float bih = bias[2 * HH + cb];
    const float brz = bias[GG + cb];
    const float brr = bias[GG + HH + cb];
    const float brh = bias[GG + 2 * HH + cb];

    for (int grp = blockIdx.x; grp < ngroups; grp += gridDim.x) {
        const int row0 = grp * R + wav * RPW;
        float h[RPW], px[RPW];
        size_t obase[RPW];
        #pragma unroll
        for (int j = 0; j < RPW; ++j) {
            h[j] = 0.f;
            int nr = row0 + j;
            obase[j] = ((size_t)((nr >> 6) * dn) * NB + (nr & 63)) * HH + cb;
        }
        if (act) {
            #pragma unroll
            for (int j = 0; j < RPW; ++j) hsT[c][wav * RPW + j] = 0.f;
        }
        const float* gb = Xin + (size_t)row0 * HH;
        #pragma unroll
        for (int j = 0; j < RPW; ++j) px[j] = gb[(size_t)j * HH + cb];   // step 0

        for (int s = 0; s < dn; ++s) {
            // publish this step's x (transposed; wave-owned columns, no barrier)
            if (act) {
                #pragma unroll
                for (int j = 0; j < RPW; ++j) xsT[c][wav * RPW + j] = px[j];
            }
            // prefetch next step's x (lands during the k-loop)
            const int sn = (s + 1 < dn) ? s + 1 : s;
            float nx[RPW];
            #pragma unroll
            for (int j = 0; j < RPW; ++j)
                nx[j] = gb[((size_t)sn * Nbatch + j) * HH + cb];

            float gz[RPW], gr[RPW], gh[RPW], az[RPW], ar[RPW], ah[RPW];
            #pragma unroll
            for (int j = 0; j < RPW; ++j) {
                gz[j] = biz; gr[j] = bir; gh[j] = bih;
                az[j] = brz; ar[j] = brr; ah[j] = brh;
            }
            #pragma unroll 10
            for (int k = 0; k < HH; ++k) {
                float4 uw = *(const float4*)&UWs[k][cb][0];
                float2 w2 = *(const float2*)&W2s[k][cb][0];
                float hv[RPW], xv[RPW];
                if constexpr (RPW == 8) {
                    float4 t0 = *(const float4*)&hsT[k][wav * RPW];
                    float4 t1 = *(const float4*)&hsT[k][wav * RPW + 4];
                    hv[0] = t0.x; hv[1] = t0.y; hv[2] = t0.z; hv[3] = t0.w;
                    hv[4] = t1.x; hv[5] = t1.y; hv[6] = t1.z; hv[7] = t1.w;
                    float4 u0 = *(const float4*)&xsT[k][wav * RPW];
                    float4 u1 = *(const float4*)&xsT[k][wav * RPW + 4];
                    xv[0] = u0.x; xv[1] = u0.y; xv[2] = u0.z; xv[3] = u0.w;
                    xv[4] = u1.x; xv[5] = u1.y; xv[6] = u1.z; xv[7] = u1.w;
                } else if constexpr (RPW == 4) {
                    float4 t  = *(const float4*)&hsT[k][wav * RPW];
                    hv[0] = t.x; hv[1] = t.y; hv[2] = t.z; hv[3] = t.w;
                    float4 u2 = *(const float4*)&xsT[k][wav * RPW];
                    xv[0] = u2.x; xv[1] = u2.y; xv[2] = u2.z; xv[3] = u2.w;
                } else if constexpr (RPW == 2) {
                    float2 t  = *(const float2*)&hsT[k][wav * RPW];
                    hv[0] = t.x; hv[1] = t.y;
                    float2 u2 = *(const float2*)&xsT[k][wav * RPW];
                    xv[0] = u2.x; xv[1] = u2.y;
                } else {
                    hv[0] = hsT[k][wav * RPW];
                    xv[0] = xsT[k][wav * RPW];
                }
                #pragma unroll
                for (int j = 0; j < RPW; ++j) {
                    az[j] += hv[j] * uw.x;
                    ar[j] += hv[j] * uw.y;
                    ah[j] += hv[j] * uw.z;
                    gz[j] += xv[j] * uw.w;
                    gr[j] += xv[j] * w2.x;
                    gh[j] += xv[j] * w2.y;
                }
            }
            #pragma unroll
            for (int j = 0; j < RPW; ++j) {
                float z  = sigm(gz[j] + az[j]);
                float r  = sigm(gr[j] + ar[j]);
                float hh = tanh_f(gh[j] + r * ah[j]);
                float hn = z * h[j] + (1.f - z) * hh;
                h[j] = hn;
                if (act) {
                    hsT[c][wav * RPW + j] = hn;
                    Xout[obase[j] + (size_t)s * NB * HH] = hn;
                }
            }
            #pragma unroll
            for (int j = 0; j < RPW; ++j) px[j] = nx[j];
        }
    }
}

// ---------------- Head: split-K partial GEMM (no bias/relu here) ----------------
__global__ __launch_bounds__(256) void dense2_kernel(
    const float* __restrict__ X,              // [MTOT,50] f32 final layer (time-major)
    const float* __restrict__ W2,             // [1600,1600] f32
    float* __restrict__ part)                 // [16,64,1600] f32 partials
{
    __shared__ float fs[8][100];              // 3.2 KB
    const int tid = threadIdx.x;
    const int c  = blockIdx.x * 256 + tid;
    const int r0 = blockIdx.y * 8;
    const int kz = blockIdx.z;
    for (int i = tid; i < 8 * 100; i += 256) {
        int r = i / 100, fl = i - r * 100;
        int f = kz * 100 + fl, j = f / HH, k = f - j * HH;
        fs[r][fl] = X[((size_t)(TTT - 32 + j) * NB + (r0 + r)) * HH + k];
    }
    __syncthreads();
    if (c < 1600) {
        float a[8] = {0, 0, 0, 0, 0, 0, 0, 0};
        const float* w = W2 + (size_t)kz * 100 * 1600 + c;
        for (int fl = 0; fl < 100; ++fl) {
            float wv = w[(size_t)fl * 1600];
            #pragma unroll
            for (int r = 0; r < 8; ++r) a[r] += fs[r][fl] * wv;
        }
        #pragma unroll
        for (int r = 0; r < 8; ++r)
            part[((size_t)kz * NB + r0 + r) * 1600 + c] = a[r];
    }
}

// ---------------- Classifier: sum partials + bias + relu, then softmax ----------------
__global__ __launch_bounds__(256) void cls_kernel(
    const float* __restrict__ part,           // [16,64,1600] f32 partials
    const float* __restrict__ b2,             // [1600] f32
    const float* __restrict__ Wc,             // [1600,41] f32
    const float* __restrict__ bc,             // [41] f32
    float* __restrict__ out)                  // [64,41] f32
{
    __shared__ float hrow[1600];
    __shared__ float lg[41];
    __shared__ float red[2];
    const int b = blockIdx.x;
    const int t = threadIdx.x;
    for (int i = t; i < 1600; i += 256) {
        float s = b2[i];
        #pragma unroll 4
        for (int kz = 0; kz < 16; ++kz)
            s += part[((size_t)kz * NB + b) * 1600 + i];
        hrow[i] = s > 0.f ? s : 0.f;
    }
    __syncthreads();
    if (t < 41) {
        float acc = bc[t];
        for (int f = 0; f < 1600; ++f) acc += hrow[f] * Wc[f * 41 + t];
        lg[t] = acc;
    }
    __syncthreads();
    if (t == 0) {
        float mx = lg[0];
        for (int i = 1; i < 41; ++i) mx = fmaxf(mx, lg[i]);
        red[0] = mx;
    }
    __syncthreads();
    if (t < 41) lg[t] = expf(lg[t] - red[0]);
    __syncthreads();
    if (t == 0) {
        float sm = 0.f;
        for (int i = 0; i < 41; ++i) sm += lg[i];
        red[1] = 1.f / sm;
    }
    __syncthreads();
    if (t < 41) out[b * 41 + t] = lg[t] * red[1];
}

extern "C" void kernel_launch(void* const* d_in, const int* in_sizes, int n_in,
                              void* d_out, int out_size, void* d_ws, size_t ws_size,
                              hipStream_t stream)
{
    const float* x   = (const float*)d_in[0];    // [64,2048,128]
    const float* W0  = (const float*)d_in[1];    // [128,150]
    const float* U0  = (const float*)d_in[2];    // [50,150]
    const float* b0  = (const float*)d_in[3];    // [2,150]
    const float* Ws  = (const float*)d_in[4];    // [5,50,150]
    const float* Us  = (const float*)d_in[5];    // [5,50,150]
    const float* bs  = (const float*)d_in[6];    // [5,2,150]
    const float* W2  = (const float*)d_in[7];    // [1600,1600]
    const float* b2  = (const float*)d_in[8];    // [1600]
    const float* Wc  = (const float*)d_in[9];    // [1600,41]
    const float* bc  = (const float*)d_in[10];   // [41]

    // R9/R12 workspace layout:
    //   region1 = MTOT*XGS floats: xg (layer 0) -> bufB (layers 1..5)
    //             part at region1 + MTOT*HH (disjoint from bufB)
    //   bufA    = MTOT*HH floats after region1
    float* region1 = (float*)d_ws;
    float* xg   = region1;
    float* bufB = region1;
    float* part = region1 + (size_t)MTOT * HH;
    float* bufA = region1 + (size_t)MTOT * XGS;

    static const int rates[6] = {32, 64, 128, 256, 512, 1024};

    // ---- layer 0: GEMM proj + gru_reg <4,1> full-unroll (R5 config, ~110 us) ----
    proj0_kernel<<<dim3(MTOT / 128, 5), 256, 0, stream>>>(x, W0, b0, xg);
    {
        int dn = TTT / rates[0], Nbatch = rates[0] * NB;   // 64, 2048
        int ngroups = Nbatch / 4;                          // R=4 for <4,1>
        int grid = ngroups < 512 ? ngroups : 512;
        gru_reg<4, 1><<<grid, 256, 0, stream>>>(xg, U0, b0, bufA, dn, Nbatch, ngroups);
    }

    // ---- layers 1..5: fused2, RPW = max with waves >= 2048 (2/SIMD) ----
    const float* cur = bufA;
    for (int l = 1; l < 6; ++l) {
        const float* Wl = Ws + (size_t)(l - 1) * HH * GG;
        const float* Ul = Us + (size_t)(l - 1) * HH * GG;
        const float* bl = bs + (size_t)(l - 1) * 2 * GG;
        int rate = rates[l];
        int Nbatch = rate * NB;
        int dn = TTT / rate;
        float* dst = (cur == bufA) ? bufB : bufA;
        if (l == 1) {                                      // Nbatch=4096: RPW=2 (2048 waves)
            int ngroups = Nbatch / 8;
            int grid = ngroups < 512 ? ngroups : 512;
            gru_fused2<4, 2><<<grid, 256, 0, stream>>>(cur, Wl, Ul, bl, dst, dn, Nbatch, ngroups);
        } else if (l == 2) {                               // Nbatch=8192: RPW=4 (2048 waves)
            int ngroups = Nbatch / 16;
            int grid = ngroups < 512 ? ngroups : 512;
            gru_fused2<4, 4><<<grid, 256, 0, stream>>>(cur, Wl, Ul, bl, dst, dn, Nbatch, ngroups);
        } else {                                           // Nbatch>=16384: RPW=8 (>=2048 waves)
            int ngroups = Nbatch / 32;
            int grid = ngroups < 512 ? ngroups : 512;
            gru_fused2<4, 8><<<grid, 256, 0, stream>>>(cur, Wl, Ul, bl, dst, dn, Nbatch, ngroups);
        }
        cur = dst;
    }
    // ping-pong A->B->A->B->A->B: final cur = bufB (disjoint from part)

    // head: split-K dense2 into partials, reduce+relu inside cls
    dense2_kernel<<<dim3(7, 8, 16), 256, 0, stream>>>(cur, W2, part);
    cls_kernel<<<NB, 256, 0, stream>>>(part, b2, Wc, bc, (float*)d_out);
}